// Round 23
// baseline (102.518 us; speedup 1.0000x reference)
//
#include <hip/hip_runtime.h>

// EuclideanCodebook: fp16 MFMA approx distance (r21 + T14 async-STAGE split:
// next B tile prefetched to registers under the current round's MFMAs, then
// ds_write after the barrier — B-load latency hidden, single LDS buffer,
// same barrier structure) + margin flag + split-K exact fp32 rescue.
// x: [N=32768][256] f32, embedding_sum: [K=2048][256] f32, usage: [K] f32
// out: quantized [N*256] f32, codes [N] f32

#define EPSV 1e-5f
#define TAU  0.4f
#define DDIM 256
#define BM   128     // rows per block (vq_mfma)
#define BCL  128     // clusters per tile
#define NPART 2      // cluster halves (1024 each)
#define NCT  8       // cluster tiles per half
#define RPB  8       // rescue rows per group
#define KSPL 4       // rescue K split
#define NROWS 32768
#define EB   32      // clusters per e-tile block (prep transpose)

typedef __attribute__((ext_vector_type(8))) _Float16 f16x8;
typedef __attribute__((ext_vector_type(4))) float f32x4;
typedef unsigned short u16;
typedef unsigned u32;
typedef unsigned long long u64;

__device__ __forceinline__ u16 f2h(float f) {
    f = fminf(fmaxf(f, -60000.f), 60000.f);   // keep fp16 finite
    const _Float16 h = (_Float16)f;
    return __builtin_bit_cast(u16, h);
}
__device__ __forceinline__ u32 umn(u32 a, u32 b) { return a < b ? a : b; }
__device__ __forceinline__ u32 umx(u32 a, u32 b) { return a > b ? a : b; }
__device__ __forceinline__ float unsort(u32 u) {
    const u32 v = (u & 0x80000000u) ? (u & 0x7FFFFFFFu) : ~u;
    return __builtin_bit_cast(float, v);
}
__device__ __forceinline__ u64 packdk(float d, int k) {
    u32 u = __builtin_bit_cast(u32, d);
    u = (u & 0x80000000u) ? ~u : (u | 0x80000000u);   // sortable float
    return ((u64)u << 32) | (u32)k;
}
__device__ __forceinline__ u32 pk2(float a, float b) {
    return (u32)f2h(a) | ((u32)f2h(b) << 16);
}

// ---------------- prep: e-side only — emb_t, eh, enorm2; zero counter -------
__global__ void prep(const float* __restrict__ esum,
                     const float* __restrict__ usage,
                     float* __restrict__ emb_t,   // [256][K] f32
                     u16* __restrict__ eh,        // [K][256] f16 bits
                     float* __restrict__ enorm2,  // [K]
                     int* __restrict__ counter,
                     int K) {
    const int b = blockIdx.x;
    if (b == 0 && threadIdx.x == 0) *counter = 0;
    __shared__ float tile[EB][DDIM + 1];   // 32 x 257 f32, pad -> no conflicts
    const int k0 = b * EB;
    const int d  = threadIdx.x;            // 256 threads
    for (int r = 0; r < EB; ++r) {
        const int k = k0 + r;
        const float u = fmaxf(usage[k], EPSV);
        const float e = esum[(size_t)k * DDIM + d] / u;
        tile[r][d] = e;
        eh[(size_t)k * DDIM + d] = f2h(e);
    }
    __syncthreads();
    if (threadIdx.x < EB) {
        const int r = threadIdx.x;
        float s = 0.f;
        #pragma unroll 8
        for (int dd = 0; dd < DDIM; ++dd) {
            const float e = tile[r][dd];
            s = fmaf(e, e, s);
        }
        enorm2[k0 + r] = s;
    }
    for (int it = 0; it < DDIM / 8; ++it) {
        const int dd   = it * 8 + (threadIdx.x >> 5);
        const int lane = threadIdx.x & 31;
        emb_t[(size_t)dd * K + k0 + lane] = tile[lane][dd];
    }
}

// ---------------- main: fp16 MFMA distance + packed (min1,min2) -------------
// r21 structure (A-resident from f32 x, XOR swizzle, XCD swizzle, packed-u32
// argmin) + T14: B(rr+1) global->VGPR issued BEFORE compute(rr); ds_write
// after the barrier (compiler's vmcnt-before-ds_write gives correctness).
__global__ __launch_bounds__(256, 2) void vq_mfma(
        const float* __restrict__ x, const u16* __restrict__ eh,
        const float* __restrict__ enorm2,
        u32* __restrict__ pp1, u32* __restrict__ pp2, int N) {
    __shared__ __align__(16) u16 Als[BM * DDIM];  // 64 KB, [128 rows][32 chunks]
    __shared__ __align__(16) u16 Bls[BCL * 64];   // 16 KB

    const int tid = threadIdx.x;
    const int l   = tid & 63;
    const int w   = tid >> 6;            // wave 0..3
    const int wr  = w >> 1, wc = w & 1;  // 2x2 wave grid (64x64 each)

    // bijective XCD swizzle: nwg = (N/BM)*NPART (512), divisible by 8
    const int nwg = (N / BM) * NPART;
    const int q   = nwg >> 3;
    const int pb  = blockIdx.x;
    const int logical = (pb & 7) * q + (pb >> 3);
    const int rowblk  = logical >> 1;    // NPART = 2
    const int part    = logical & 1;
    const int n0      = rowblk * BM;
    const int cbase   = part * 1024;

    // B staging source chunk swizzle: row&7 == (l>>3)&7, chunk == l&7
    const int sgc = (l & 7) ^ ((l >> 3) & 7);

    // T14 register prefetch buffer: 4 x 16B of the next B tile
    uint4 breg0, breg1, breg2, breg3;
    auto issueB = [&](int rr) {
        const int c0_    = cbase + (rr >> 2) * BCL;
        const int colof_ = (rr & 3) * 64;
        const u16* bbase = eh + colof_ + sgc * 8;
        breg0 = *(const uint4*)(bbase + (size_t)(c0_ + (w * 4 + 0) * 8 + (l >> 3)) * DDIM);
        breg1 = *(const uint4*)(bbase + (size_t)(c0_ + (w * 4 + 1) * 8 + (l >> 3)) * DDIM);
        breg2 = *(const uint4*)(bbase + (size_t)(c0_ + (w * 4 + 2) * 8 + (l >> 3)) * DDIM);
        breg3 = *(const uint4*)(bbase + (size_t)(c0_ + (w * 4 + 3) * 8 + (l >> 3)) * DDIM);
    };
    auto writeB = [&]() {
        // same slots global_load_lds used: base + lane*16
        *(uint4*)((char*)Bls + (w * 4 + 0) * 1024 + l * 16) = breg0;
        *(uint4*)((char*)Bls + (w * 4 + 1) * 1024 + l * 16) = breg1;
        *(uint4*)((char*)Bls + (w * 4 + 2) * 1024 + l * 16) = breg2;
        *(uint4*)((char*)Bls + (w * 4 + 3) * 1024 + l * 16) = breg3;
    };

    issueB(0);                           // B(0) loads fly under A conversion

    // ---- stage A once: LDS[row][chunk c] = fp16(x[row][gc*8..gc*8+7]),
    //      gc = (c&24)|((c&7)^(row&7)). f32 loads coalesced per row.
    #pragma unroll
    for (int j = 0; j < 16; ++j) {
        const int slot = j * 256 + tid;            // 0..4095
        const int row  = slot >> 5;                // 0..127
        const int c    = slot & 31;                // LDS chunk
        const int gc   = (c & 24) | ((c & 7) ^ (row & 7));
        const float* xp = x + (size_t)(n0 + row) * DDIM + gc * 8;
        const float4 v0 = *(const float4*)xp;
        const float4 v1 = *(const float4*)(xp + 4);
        uint4 hv;
        hv.x = pk2(v0.x, v0.y);
        hv.y = pk2(v0.z, v0.w);
        hv.z = pk2(v1.x, v1.y);
        hv.w = pk2(v1.z, v1.w);
        *(uint4*)((char*)Als + slot * 16) = hv;
    }

    u32 m1p[4][4], m2p[4][4];
    #pragma unroll
    for (int a = 0; a < 4; ++a)
        #pragma unroll
        for (int b = 0; b < 4; ++b) { m1p[a][b] = 0xFFFFFFFFu; m2p[a][b] = 0xFFFFFFFFu; }

    writeB();                            // B(0) -> LDS (waits its own loads)
    __syncthreads();                     // A + B(0) resident

    int rr = 0;
    for (int ct = 0; ct < NCT; ++ct) {
        const int c0 = cbase + ct * BCL;
        f32x4 acc[4][4];
        #pragma unroll
        for (int a = 0; a < 4; ++a)
            #pragma unroll
            for (int b = 0; b < 4; ++b) acc[a][b] = (f32x4){0.f, 0.f, 0.f, 0.f};

        for (int ch = 0; ch < 4; ++ch, ++rr) {
            if (rr + 1 < NCT * 4) issueB(rr + 1);   // loads in flight under MFMAs

            #pragma unroll
            for (int ks = 0; ks < 2; ++ks) {
                f16x8 af[4], bfr[4];
                #pragma unroll
                for (int f = 0; f < 4; ++f) {
                    const int arow   = wr * 64 + f * 16 + (l & 15);
                    const int achunk = ch * 8 + (((ks * 4 + (l >> 4))) ^ (l & 7)); // arow&7==l&7
                    af[f] = *(const f16x8*)((const char*)Als + arow * 512 + achunk * 16);
                    const int brow = wc * 64 + f * 16 + (l & 15);
                    const int bc   = (ks * 4 + (l >> 4)) ^ (l & 7);
                    bfr[f] = *(const f16x8*)((const char*)Bls + brow * 128 + bc * 16);
                }
                #pragma unroll
                for (int fm = 0; fm < 4; ++fm)
                    #pragma unroll
                    for (int fn = 0; fn < 4; ++fn)
                        acc[fm][fn] = __builtin_amdgcn_mfma_f32_16x16x32_f16(
                            af[fm], bfr[fn], acc[fm][fn], 0, 0, 0);
            }
            __syncthreads();                        // all waves done reading Bls
            if (rr + 1 < NCT * 4) {
                writeB();                           // B(rr+1) -> LDS
            }
            __syncthreads();                        // Bls ready for next round
        }

        // fold: pack (s,k) sortable and track (min1, min2) as u32
        #pragma unroll
        for (int fn = 0; fn < 4; ++fn) {
            const int k = c0 + wc * 64 + fn * 16 + (l & 15);
            const float en = enorm2[k];
            #pragma unroll
            for (int fm = 0; fm < 4; ++fm)
                #pragma unroll
                for (int i = 0; i < 4; ++i) {
                    const float s = fmaf(-2.0f, acc[fm][fn][i], en);
                    u32 u = __builtin_bit_cast(u32, s);
                    u = ((int)u < 0) ? ~u : (u | 0x80000000u);
                    const u32 p = (u & 0xFFFFF800u) | (u32)k;
                    m2p[fm][i] = umn(m2p[fm][i], umx(p, m1p[fm][i]));
                    m1p[fm][i] = umn(m1p[fm][i], p);
                }
        }
    }

    // reduce across the 16 lanes (l&15) sharing each row
    #pragma unroll
    for (int fm = 0; fm < 4; ++fm)
        #pragma unroll
        for (int i = 0; i < 4; ++i) {
            u32 p1 = m1p[fm][i], p2 = m2p[fm][i];
            #pragma unroll
            for (int mask = 1; mask < 16; mask <<= 1) {
                const u32 o1 = (u32)__shfl_xor((int)p1, mask, 64);
                const u32 o2 = (u32)__shfl_xor((int)p2, mask, 64);
                p2 = umn(umn(p2, o2), umx(p1, o1));
                p1 = umn(p1, o1);
            }
            m1p[fm][i] = p1; m2p[fm][i] = p2;
        }

    // merge the two wave-columns via LDS, write per-(part,row) partials
    __syncthreads();
    u32* S1 = (u32*)Bls;                   // [128]
    u32* S2 = (u32*)((char*)Bls + 512);    // [128]
    if (wc == 0 && (l & 15) == 0) {
        #pragma unroll
        for (int fm = 0; fm < 4; ++fm)
            #pragma unroll
            for (int i = 0; i < 4; ++i) {
                const int r = wr * 64 + fm * 16 + (l >> 4) * 4 + i;
                S1[r] = m1p[fm][i]; S2[r] = m2p[fm][i];
            }
    }
    __syncthreads();
    if (wc == 1 && (l & 15) == 0) {
        #pragma unroll
        for (int fm = 0; fm < 4; ++fm)
            #pragma unroll
            for (int i = 0; i < 4; ++i) {
                const int r = wr * 64 + fm * 16 + (l >> 4) * 4 + i;
                const u32 o1 = S1[r], o2 = S2[r];
                u32 p1 = m1p[fm][i], p2 = m2p[fm][i];
                const u32 M2 = umn(umn(p2, o2), umx(p1, o1));
                const u32 M1 = umn(p1, o1);
                const int n = n0 + r;
                pp1[(size_t)part * N + n] = M1;
                pp2[(size_t)part * N + n] = M2;
            }
    }
}

// ---------------- combine halves -> codes + flags + rescue list -------------
__global__ void combine(const u32* __restrict__ pp1, const u32* __restrict__ pp2,
                        int* __restrict__ codes_i, int* __restrict__ flags,
                        int* __restrict__ list, int* __restrict__ counter,
                        u64* __restrict__ packed, int N) {
    const int n = blockIdx.x * 256 + threadIdx.x;
    u32 p1 = pp1[n], p2 = pp2[n];
    #pragma unroll
    for (int j = 1; j < NPART; ++j) {
        const u32 o1 = pp1[(size_t)j * N + n], o2 = pp2[(size_t)j * N + n];
        p2 = umn(umn(p2, o2), umx(p1, o1));
        p1 = umn(p1, o1);
    }
    codes_i[n] = (int)(p1 & 0x7FFu);
    const float m1f = unsort(p1 & 0xFFFFF800u);
    const float m2f = unsort(p2 & 0xFFFFF800u);
    const int fl = (m2f - m1f < TAU) ? 1 : 0;
    flags[n] = fl;
    if (fl) {
        packed[n] = 0xFFFFFFFFFFFFFFFFull;
        const int idx = atomicAdd(counter, 1);
        list[idx] = n;
    }
}

// ---------------- rescue_c: exact fp32, 8 rows x 512-cluster work items -----
__global__ __launch_bounds__(256) void rescue_c(
        const float* __restrict__ x, const float* __restrict__ emb_t,
        const float* __restrict__ enorm2,
        const int* __restrict__ list, const int* __restrict__ counter,
        u64* __restrict__ packed, int K) {
    __shared__ float xs[RPB][DDIM];   // 8 KB
    const int t = threadIdx.x;
    const int l = t & 63;
    int cnt = *counter;
    cnt = cnt < 0 ? 0 : (cnt > NROWS ? NROWS : cnt);   // defensive clamp
    if (cnt == 0) return;
    const int nblk  = (cnt + RPB - 1) / RPB;
    const int items = nblk * KSPL;
    const int kc    = K / KSPL;       // 512

    for (int wi = blockIdx.x; wi < items; wi += gridDim.x) {
        const int g = wi >> 2;        // KSPL = 4
        const int q = wi & 3;
        const int base = g * RPB;
        int rows[RPB];
        #pragma unroll
        for (int r = 0; r < RPB; ++r) {
            int idx = base + r;
            rows[r] = list[idx < cnt ? idx : cnt - 1];
        }
        __syncthreads();              // previous iteration done reading xs
        #pragma unroll
        for (int r = 0; r < RPB; ++r)
            xs[r][t] = x[(size_t)rows[r] * DDIM + t];
        __syncthreads();

        float acc[RPB][2];
        #pragma unroll
        for (int r = 0; r < RPB; ++r) { acc[r][0] = 0.f; acc[r][1] = 0.f; }

        const float* eb = emb_t + q * kc + 2 * t;
        #pragma unroll 8
        for (int d = 0; d < DDIM; ++d) {
            const float2 e = *(const float2*)&eb[(size_t)d * K];
            #pragma unroll
            for (int r = 0; r < RPB; ++r) {
                const float xv = xs[r][d];
                acc[r][0] = fmaf(xv, e.x, acc[r][0]);
                acc[r][1] = fmaf(xv, e.y, acc[r][1]);
            }
        }

        const int k0 = q * kc + 2 * t;
        const float en0 = enorm2[k0], en1 = enorm2[k0 + 1];
        #pragma unroll
        for (int r = 0; r < RPB; ++r) {
            const float s0 = fmaf(-2.0f, acc[r][0], en0);
            const float s1 = fmaf(-2.0f, acc[r][1], en1);
            float bd = s0; int bk = k0;
            if (s1 < bd) { bd = s1; bk = k0 + 1; }
            #pragma unroll
            for (int m = 1; m < 64; m <<= 1) {
                const float od = __shfl_xor(bd, m, 64);
                const int   ok = __shfl_xor(bk, m, 64);
                if (od < bd || (od == bd && ok < bk)) { bd = od; bk = ok; }
            }
            if (l == 0) atomicMin(&packed[rows[r]], packdk(bd, bk));
        }
    }
}

// ---------------- gather: codes + quantized on the fly ----------------------
__global__ void gather_q(const float* __restrict__ esum,
                         const float* __restrict__ usage,
                         const int* __restrict__ codes_i,
                         const int* __restrict__ flags,
                         const u64* __restrict__ packed,
                         float* __restrict__ qout,
                         float* __restrict__ codes_f) {
    const int n = blockIdx.x * 4 + (threadIdx.x >> 6);
    const int c = threadIdx.x & 63;
    int k = codes_i[n];
    if (flags[n]) k = (int)(packed[n] & 0xFFFFFFFFull);
    if (c == 0) codes_f[n] = (float)k;
    const float u = fmaxf(usage[k], EPSV);
    float4 v = *(const float4*)&esum[(size_t)k * DDIM + c * 4];
    v.x /= u; v.y /= u; v.z /= u; v.w /= u;
    *(float4*)&qout[(size_t)n * DDIM + c * 4] = v;
}

extern "C" void kernel_launch(void* const* d_in, const int* in_sizes, int n_in,
                              void* d_out, int out_size, void* d_ws, size_t ws_size,
                              hipStream_t stream) {
    const float* x     = (const float*)d_in[0];
    const float* esum  = (const float*)d_in[1];
    const float* usage = (const float*)d_in[2];
    const int K = in_sizes[2];                 // 2048
    const int N = in_sizes[0] / DDIM;          // 32768

    // workspace layout (packed first: 8B alignment)
    char* p = (char*)d_ws;
    u64*   packed  = (u64*)p;                  p += (size_t)N * 8;             // 256 KB
    float* emb_t   = (float*)p;                p += (size_t)K * DDIM * 4;      // 2 MB
    float* enorm2  = (float*)p;                p += (size_t)K * 4;
    u32*   pp1     = (u32*)p;                  p += (size_t)NPART * N * 4;     // 256 KB
    u32*   pp2     = (u32*)p;                  p += (size_t)NPART * N * 4;     // 256 KB
    int*   codes_i = (int*)p;                  p += (size_t)N * 4;
    int*   flags   = (int*)p;                  p += (size_t)N * 4;
    int*   list    = (int*)p;                  p += (size_t)N * 4;
    int*   counter = (int*)p;                  p += 256;
    u16*   eh      = (u16*)p;                  p += (size_t)K * DDIM * 2;      // 1 MB

    float* qout    = (float*)d_out;            // N*256
    float* codes_f = qout + (size_t)N * DDIM;  // N

    prep<<<K / EB, 256, 0, stream>>>(esum, usage, emb_t, eh, enorm2, counter, K);
    vq_mfma<<<(N / BM) * NPART, 256, 0, stream>>>(x, eh, enorm2, pp1, pp2, N);
    combine<<<N / 256, 256, 0, stream>>>(pp1, pp2, codes_i, flags,
                                         list, counter, packed, N);
    rescue_c<<<1024, 256, 0, stream>>>(x, emb_t, enorm2, list, counter, packed, K);
    gather_q<<<N / 4, 256, 0, stream>>>(esum, usage, codes_i, flags, packed,
                                        qout, codes_f);
}

// Round 24
// 101.172 us; speedup vs baseline: 1.0133x; 1.0133x over previous
//
#include <hip/hip_runtime.h>

// EuclideanCodebook: fp16 MFMA approx distance (A-resident LDS staged from
// f32 x with in-kernel fp16 conversion + swizzled ds_write; B re-staged per
// tile via global_load_lds; XOR-swizzled LDS; bijective XCD swizzle;
// packed-u32 argmin state) + top-2 margin flag + split-K exact fp32 rescue.
// Best-measured configuration (r21, 101.2 us). Schedule attacks (explicit
// dbuf, counted-vmcnt, T14 reg-prefetch) all measured neutral at the
// AGPR-imposed 2-waves/SIMD occupancy — this is the structural plateau.
// x: [N=32768][256] f32, embedding_sum: [K=2048][256] f32, usage: [K] f32
// out: quantized [N*256] f32, codes [N] f32

#define EPSV 1e-5f
#define TAU  0.4f
#define DDIM 256
#define BM   128     // rows per block (vq_mfma)
#define BCL  128     // clusters per tile
#define NPART 2      // cluster halves (1024 each)
#define NCT  8       // cluster tiles per half
#define RPB  8       // rescue rows per group
#define KSPL 4       // rescue K split
#define NROWS 32768
#define EB   32      // clusters per e-tile block (prep transpose)

typedef __attribute__((ext_vector_type(8))) _Float16 f16x8;
typedef __attribute__((ext_vector_type(4))) float f32x4;
typedef unsigned short u16;
typedef unsigned u32;
typedef unsigned long long u64;

__device__ __forceinline__ u16 f2h(float f) {
    f = fminf(fmaxf(f, -60000.f), 60000.f);   // keep fp16 finite
    const _Float16 h = (_Float16)f;
    return __builtin_bit_cast(u16, h);
}
__device__ __forceinline__ u32 umn(u32 a, u32 b) { return a < b ? a : b; }
__device__ __forceinline__ u32 umx(u32 a, u32 b) { return a > b ? a : b; }
__device__ __forceinline__ float unsort(u32 u) {
    const u32 v = (u & 0x80000000u) ? (u & 0x7FFFFFFFu) : ~u;
    return __builtin_bit_cast(float, v);
}
__device__ __forceinline__ u64 packdk(float d, int k) {
    u32 u = __builtin_bit_cast(u32, d);
    u = (u & 0x80000000u) ? ~u : (u | 0x80000000u);   // sortable float
    return ((u64)u << 32) | (u32)k;
}
__device__ __forceinline__ u32 pk2(float a, float b) {
    return (u32)f2h(a) | ((u32)f2h(b) << 16);
}

// ---------------- prep: e-side only — emb_t, eh, enorm2; zero counter -------
__global__ void prep(const float* __restrict__ esum,
                     const float* __restrict__ usage,
                     float* __restrict__ emb_t,   // [256][K] f32
                     u16* __restrict__ eh,        // [K][256] f16 bits
                     float* __restrict__ enorm2,  // [K]
                     int* __restrict__ counter,
                     int K) {
    const int b = blockIdx.x;
    if (b == 0 && threadIdx.x == 0) *counter = 0;
    __shared__ float tile[EB][DDIM + 1];   // 32 x 257 f32, pad -> no conflicts
    const int k0 = b * EB;
    const int d  = threadIdx.x;            // 256 threads
    for (int r = 0; r < EB; ++r) {
        const int k = k0 + r;
        const float u = fmaxf(usage[k], EPSV);
        const float e = esum[(size_t)k * DDIM + d] / u;
        tile[r][d] = e;
        eh[(size_t)k * DDIM + d] = f2h(e);
    }
    __syncthreads();
    if (threadIdx.x < EB) {
        const int r = threadIdx.x;
        float s = 0.f;
        #pragma unroll 8
        for (int dd = 0; dd < DDIM; ++dd) {
            const float e = tile[r][dd];
            s = fmaf(e, e, s);
        }
        enorm2[k0 + r] = s;
    }
    for (int it = 0; it < DDIM / 8; ++it) {
        const int dd   = it * 8 + (threadIdx.x >> 5);
        const int lane = threadIdx.x & 31;
        emb_t[(size_t)dd * K + k0 + lane] = tile[lane][dd];
    }
}

// ---------------- main: fp16 MFMA distance + packed (min1,min2) -------------
// A staged once per block directly from f32 x: coalesced float4 pair loads,
// in-register f2h, ds_write_b128 to the swizzled slot (reg-staging — the
// swizzled dest is legal, unlike global_load_lds).
__global__ __launch_bounds__(256, 2) void vq_mfma(
        const float* __restrict__ x, const u16* __restrict__ eh,
        const float* __restrict__ enorm2,
        u32* __restrict__ pp1, u32* __restrict__ pp2, int N) {
    __shared__ __align__(16) u16 Als[BM * DDIM];  // 64 KB, [128 rows][32 chunks]
    __shared__ __align__(16) u16 Bls[BCL * 64];   // 16 KB

    const int tid = threadIdx.x;
    const int l   = tid & 63;
    const int w   = tid >> 6;            // wave 0..3
    const int wr  = w >> 1, wc = w & 1;  // 2x2 wave grid (64x64 each)

    // bijective XCD swizzle: nwg = (N/BM)*NPART (512), divisible by 8
    const int nwg = (N / BM) * NPART;
    const int q   = nwg >> 3;
    const int pb  = blockIdx.x;
    const int logical = (pb & 7) * q + (pb >> 3);
    const int rowblk  = logical >> 1;    // NPART = 2
    const int part    = logical & 1;
    const int n0      = rowblk * BM;
    const int cbase   = part * 1024;

    // ---- stage A once: LDS[row][chunk c] = fp16(x[row][gc*8..gc*8+7]),
    //      gc = (c&24)|((c&7)^(row&7)). f32 loads coalesced per row.
    #pragma unroll
    for (int j = 0; j < 16; ++j) {
        const int slot = j * 256 + tid;            // 0..4095
        const int row  = slot >> 5;                // 0..127
        const int c    = slot & 31;                // LDS chunk
        const int gc   = (c & 24) | ((c & 7) ^ (row & 7));
        const float* xp = x + (size_t)(n0 + row) * DDIM + gc * 8;
        const float4 v0 = *(const float4*)xp;
        const float4 v1 = *(const float4*)(xp + 4);
        uint4 hv;
        hv.x = pk2(v0.x, v0.y);
        hv.y = pk2(v0.z, v0.w);
        hv.z = pk2(v1.x, v1.y);
        hv.w = pk2(v1.z, v1.w);
        *(uint4*)((char*)Als + slot * 16) = hv;
    }

    u32 m1p[4][4], m2p[4][4];
    #pragma unroll
    for (int a = 0; a < 4; ++a)
        #pragma unroll
        for (int b = 0; b < 4; ++b) { m1p[a][b] = 0xFFFFFFFFu; m2p[a][b] = 0xFFFFFFFFu; }

    // B staging source chunk swizzle: row&7 == (l>>3)&7, chunk == l&7
    const int sgc = (l & 7) ^ ((l >> 3) & 7);

    __syncthreads();                     // A resident

    for (int ct = 0; ct < NCT; ++ct) {
        const int c0 = cbase + ct * BCL;
        f32x4 acc[4][4];
        #pragma unroll
        for (int a = 0; a < 4; ++a)
            #pragma unroll
            for (int b = 0; b < 4; ++b) acc[a][b] = (f32x4){0.f, 0.f, 0.f, 0.f};

        for (int ch = 0; ch < 4; ++ch) {       // 256 = 4 x 64 inner dims
            const int colof = ch * 64;

            __syncthreads();                   // previous round done reading Bls
            #pragma unroll
            for (int j = 0; j < 4; ++j) {
                const int r = (w * 4 + j) * 8 + (l >> 3);
                const u16* gb = eh + (size_t)(c0 + r) * DDIM + colof + sgc * 8;
                __builtin_amdgcn_global_load_lds(
                    (const __attribute__((address_space(1))) void*)gb,
                    (__attribute__((address_space(3))) void*)((char*)Bls + (w * 4 + j) * 1024),
                    16, 0, 0);
            }
            __syncthreads();                   // B staged

            #pragma unroll
            for (int ks = 0; ks < 2; ++ks) {
                f16x8 af[4], bfr[4];
                #pragma unroll
                for (int f = 0; f < 4; ++f) {
                    const int arow   = wr * 64 + f * 16 + (l & 15);
                    const int achunk = ch * 8 + (((ks * 4 + (l >> 4))) ^ (l & 7)); // arow&7==l&7
                    af[f] = *(const f16x8*)((const char*)Als + arow * 512 + achunk * 16);
                    const int brow = wc * 64 + f * 16 + (l & 15);
                    const int bc   = (ks * 4 + (l >> 4)) ^ (l & 7);
                    bfr[f] = *(const f16x8*)((const char*)Bls + brow * 128 + bc * 16);
                }
                #pragma unroll
                for (int fm = 0; fm < 4; ++fm)
                    #pragma unroll
                    for (int fn = 0; fn < 4; ++fn)
                        acc[fm][fn] = __builtin_amdgcn_mfma_f32_16x16x32_f16(
                            af[fm], bfr[fn], acc[fm][fn], 0, 0, 0);
            }
        }

        // fold: pack (s,k) sortable and track (min1, min2) as u32
        #pragma unroll
        for (int fn = 0; fn < 4; ++fn) {
            const int k = c0 + wc * 64 + fn * 16 + (l & 15);
            const float en = enorm2[k];
            #pragma unroll
            for (int fm = 0; fm < 4; ++fm)
                #pragma unroll
                for (int i = 0; i < 4; ++i) {
                    const float s = fmaf(-2.0f, acc[fm][fn][i], en);
                    u32 u = __builtin_bit_cast(u32, s);
                    u = ((int)u < 0) ? ~u : (u | 0x80000000u);
                    const u32 p = (u & 0xFFFFF800u) | (u32)k;
                    m2p[fm][i] = umn(m2p[fm][i], umx(p, m1p[fm][i]));
                    m1p[fm][i] = umn(m1p[fm][i], p);
                }
        }
    }

    // reduce across the 16 lanes (l&15) sharing each row
    #pragma unroll
    for (int fm = 0; fm < 4; ++fm)
        #pragma unroll
        for (int i = 0; i < 4; ++i) {
            u32 p1 = m1p[fm][i], p2 = m2p[fm][i];
            #pragma unroll
            for (int mask = 1; mask < 16; mask <<= 1) {
                const u32 o1 = (u32)__shfl_xor((int)p1, mask, 64);
                const u32 o2 = (u32)__shfl_xor((int)p2, mask, 64);
                p2 = umn(umn(p2, o2), umx(p1, o1));
                p1 = umn(p1, o1);
            }
            m1p[fm][i] = p1; m2p[fm][i] = p2;
        }

    // merge the two wave-columns via LDS, write per-(part,row) partials
    __syncthreads();
    u32* S1 = (u32*)Bls;                   // [128]
    u32* S2 = (u32*)((char*)Bls + 512);    // [128]
    if (wc == 0 && (l & 15) == 0) {
        #pragma unroll
        for (int fm = 0; fm < 4; ++fm)
            #pragma unroll
            for (int i = 0; i < 4; ++i) {
                const int r = wr * 64 + fm * 16 + (l >> 4) * 4 + i;
                S1[r] = m1p[fm][i]; S2[r] = m2p[fm][i];
            }
    }
    __syncthreads();
    if (wc == 1 && (l & 15) == 0) {
        #pragma unroll
        for (int fm = 0; fm < 4; ++fm)
            #pragma unroll
            for (int i = 0; i < 4; ++i) {
                const int r = wr * 64 + fm * 16 + (l >> 4) * 4 + i;
                const u32 o1 = S1[r], o2 = S2[r];
                u32 p1 = m1p[fm][i], p2 = m2p[fm][i];
                const u32 M2 = umn(umn(p2, o2), umx(p1, o1));
                const u32 M1 = umn(p1, o1);
                const int n = n0 + r;
                pp1[(size_t)part * N + n] = M1;
                pp2[(size_t)part * N + n] = M2;
            }
    }
}

// ---------------- combine halves -> codes + flags + rescue list -------------
__global__ void combine(const u32* __restrict__ pp1, const u32* __restrict__ pp2,
                        int* __restrict__ codes_i, int* __restrict__ flags,
                        int* __restrict__ list, int* __restrict__ counter,
                        u64* __restrict__ packed, int N) {
    const int n = blockIdx.x * 256 + threadIdx.x;
    u32 p1 = pp1[n], p2 = pp2[n];
    #pragma unroll
    for (int j = 1; j < NPART; ++j) {
        const u32 o1 = pp1[(size_t)j * N + n], o2 = pp2[(size_t)j * N + n];
        p2 = umn(umn(p2, o2), umx(p1, o1));
        p1 = umn(p1, o1);
    }
    codes_i[n] = (int)(p1 & 0x7FFu);
    const float m1f = unsort(p1 & 0xFFFFF800u);
    const float m2f = unsort(p2 & 0xFFFFF800u);
    const int fl = (m2f - m1f < TAU) ? 1 : 0;
    flags[n] = fl;
    if (fl) {
        packed[n] = 0xFFFFFFFFFFFFFFFFull;
        const int idx = atomicAdd(counter, 1);
        list[idx] = n;
    }
}

// ---------------- rescue_c: exact fp32, 8 rows x 512-cluster work items -----
__global__ __launch_bounds__(256) void rescue_c(
        const float* __restrict__ x, const float* __restrict__ emb_t,
        const float* __restrict__ enorm2,
        const int* __restrict__ list, const int* __restrict__ counter,
        u64* __restrict__ packed, int K) {
    __shared__ float xs[RPB][DDIM];   // 8 KB
    const int t = threadIdx.x;
    const int l = t & 63;
    int cnt = *counter;
    cnt = cnt < 0 ? 0 : (cnt > NROWS ? NROWS : cnt);   // defensive clamp
    if (cnt == 0) return;
    const int nblk  = (cnt + RPB - 1) / RPB;
    const int items = nblk * KSPL;
    const int kc    = K / KSPL;       // 512

    for (int wi = blockIdx.x; wi < items; wi += gridDim.x) {
        const int g = wi >> 2;        // KSPL = 4
        const int q = wi & 3;
        const int base = g * RPB;
        int rows[RPB];
        #pragma unroll
        for (int r = 0; r < RPB; ++r) {
            int idx = base + r;
            rows[r] = list[idx < cnt ? idx : cnt - 1];
        }
        __syncthreads();              // previous iteration done reading xs
        #pragma unroll
        for (int r = 0; r < RPB; ++r)
            xs[r][t] = x[(size_t)rows[r] * DDIM + t];
        __syncthreads();

        float acc[RPB][2];
        #pragma unroll
        for (int r = 0; r < RPB; ++r) { acc[r][0] = 0.f; acc[r][1] = 0.f; }

        const float* eb = emb_t + q * kc + 2 * t;
        #pragma unroll 8
        for (int d = 0; d < DDIM; ++d) {
            const float2 e = *(const float2*)&eb[(size_t)d * K];
            #pragma unroll
            for (int r = 0; r < RPB; ++r) {
                const float xv = xs[r][d];
                acc[r][0] = fmaf(xv, e.x, acc[r][0]);
                acc[r][1] = fmaf(xv, e.y, acc[r][1]);
            }
        }

        const int k0 = q * kc + 2 * t;
        const float en0 = enorm2[k0], en1 = enorm2[k0 + 1];
        #pragma unroll
        for (int r = 0; r < RPB; ++r) {
            const float s0 = fmaf(-2.0f, acc[r][0], en0);
            const float s1 = fmaf(-2.0f, acc[r][1], en1);
            float bd = s0; int bk = k0;
            if (s1 < bd) { bd = s1; bk = k0 + 1; }
            #pragma unroll
            for (int m = 1; m < 64; m <<= 1) {
                const float od = __shfl_xor(bd, m, 64);
                const int   ok = __shfl_xor(bk, m, 64);
                if (od < bd || (od == bd && ok < bk)) { bd = od; bk = ok; }
            }
            if (l == 0) atomicMin(&packed[rows[r]], packdk(bd, bk));
        }
    }
}

// ---------------- gather: codes + quantized on the fly ----------------------
__global__ void gather_q(const float* __restrict__ esum,
                         const float* __restrict__ usage,
                         const int* __restrict__ codes_i,
                         const int* __restrict__ flags,
                         const u64* __restrict__ packed,
                         float* __restrict__ qout,
                         float* __restrict__ codes_f) {
    const int n = blockIdx.x * 4 + (threadIdx.x >> 6);
    const int c = threadIdx.x & 63;
    int k = codes_i[n];
    if (flags[n]) k = (int)(packed[n] & 0xFFFFFFFFull);
    if (c == 0) codes_f[n] = (float)k;
    const float u = fmaxf(usage[k], EPSV);
    float4 v = *(const float4*)&esum[(size_t)k * DDIM + c * 4];
    v.x /= u; v.y /= u; v.z /= u; v.w /= u;
    *(float4*)&qout[(size_t)n * DDIM + c * 4] = v;
}

extern "C" void kernel_launch(void* const* d_in, const int* in_sizes, int n_in,
                              void* d_out, int out_size, void* d_ws, size_t ws_size,
                              hipStream_t stream) {
    const float* x     = (const float*)d_in[0];
    const float* esum  = (const float*)d_in[1];
    const float* usage = (const float*)d_in[2];
    const int K = in_sizes[2];                 // 2048
    const int N = in_sizes[0] / DDIM;          // 32768

    // workspace layout (packed first: 8B alignment)
    char* p = (char*)d_ws;
    u64*   packed  = (u64*)p;                  p += (size_t)N * 8;             // 256 KB
    float* emb_t   = (float*)p;                p += (size_t)K * DDIM * 4;      // 2 MB
    float* enorm2  = (float*)p;                p += (size_t)K * 4;
    u32*   pp1     = (u32*)p;                  p += (size_t)NPART * N * 4;     // 256 KB
    u32*   pp2     = (u32*)p;                  p += (size_t)NPART * N * 4;     // 256 KB
    int*   codes_i = (int*)p;                  p += (size_t)N * 4;
    int*   flags   = (int*)p;                  p += (size_t)N * 4;
    int*   list    = (int*)p;                  p += (size_t)N * 4;
    int*   counter = (int*)p;                  p += 256;
    u16*   eh      = (u16*)p;                  p += (size_t)K * DDIM * 2;      // 1 MB

    float* qout    = (float*)d_out;            // N*256
    float* codes_f = qout + (size_t)N * DDIM;  // N

    prep<<<K / EB, 256, 0, stream>>>(esum, usage, emb_t, eh, enorm2, counter, K);
    vq_mfma<<<(N / BM) * NPART, 256, 0, stream>>>(x, eh, enorm2, pp1, pp2, N);
    combine<<<N / 256, 256, 0, stream>>>(pp1, pp2, codes_i, flags,
                                         list, counter, packed, N);
    rescue_c<<<1024, 256, 0, stream>>>(x, emb_t, enorm2, list, counter, packed, K);
    gather_q<<<N / 4, 256, 0, stream>>>(esum, usage, codes_i, flags, packed,
                                        qout, codes_f);
}